// Round 5
// baseline (1007.403 us; speedup 1.0000x reference)
//
#include <hip/hip_runtime.h>

// ---------- types ----------
typedef __bf16 bf16x8 __attribute__((ext_vector_type(8)));
typedef float  f32x4  __attribute__((ext_vector_type(4)));
typedef unsigned short us8 __attribute__((ext_vector_type(8)));

__device__ __forceinline__ unsigned short f2bf(float f) {
  unsigned int u = __builtin_bit_cast(unsigned int, f);
  u += 0x7FFFu + ((u >> 16) & 1u);   // round-to-nearest-even
  return (unsigned short)(u >> 16);
}
__device__ __forceinline__ float bf2f(unsigned short h) {
  unsigned int u = ((unsigned int)h) << 16;
  return __builtin_bit_cast(float, u);
}
__device__ __forceinline__ float sigmoid_f(float x) {
  return 1.f / (1.f + __expf(-x));
}
// NaN-safe fast tanh: 1 - 2/(e^{2x}+1)
__device__ __forceinline__ float tanh_f(float x) {
  float e = __expf(2.f * x);
  return 1.f - 2.f / (e + 1.f);
}

// ---------- f32 -> bf16 cast, 8 elems/thread ----------
__global__ void cast_f32_bf16(const float* __restrict__ in,
                              unsigned short* __restrict__ out, long n) {
  long i = ((long)blockIdx.x * blockDim.x + threadIdx.x) * 8;
  if (i >= n) return;
  f32x4 a = *(const f32x4*)(in + i);
  f32x4 b = *(const f32x4*)(in + i + 4);
  us8 o;
  o[0] = f2bf(a[0]); o[1] = f2bf(a[1]); o[2] = f2bf(a[2]); o[3] = f2bf(a[3]);
  o[4] = f2bf(b[0]); o[5] = f2bf(b[1]); o[6] = f2bf(b[2]); o[7] = f2bf(b[3]);
  *(us8*)(out + i) = o;
}

#define GLOAD(gp, lp) __builtin_amdgcn_global_load_lds( \
    (const __attribute__((address_space(1))) unsigned int*)(gp), \
    (__attribute__((address_space(3))) unsigned int*)(lp), 16, 0, 0)

// ---------- Fused GRU cell: BK=64 + XOR swizzle + counted vmcnt ----------
// Block tile: 128 batch-rows x 64 H-cols (x3 gates). 4 waves (2M x 2C),
// wave tile 64x32 per gate-accumulator. Acc sets: r, z, i_n, h_n.
// K-tiles of 64: t=0..7 over inp/wih (K=512), t=8..23 over h/whh (K=1024).
// LDS rows are 128B = 8 x 16B slots; stored with inverse-swizzled global
// source (linear gload_lds dest), read at slot = kblock ^ (row&7).
// Per tile: 10 gload_lds/thread; s_waitcnt vmcnt(10) keeps next tile in flight.
__global__ __launch_bounds__(256, 2) void fused_gru(
    const unsigned short* __restrict__ inp_b,
    const unsigned short* __restrict__ h_b,
    const unsigned short* __restrict__ wih,
    const unsigned short* __restrict__ whh,
    const float* __restrict__ b_ih,
    const float* __restrict__ b_hh,
    const float* __restrict__ hidden,      // [B,1024] f32
    float* __restrict__ hnew_f32,
    unsigned short* __restrict__ hnew_b)
{
  __shared__ unsigned short lsA[2][128 * 64];      // 2 x 16KB
  __shared__ unsigned short lsW[2][3 * 64 * 64];   // 2 x 24KB (3 gate panels)

  const int tid  = threadIdx.x;
  const int lane = tid & 63;
  const int wave = tid >> 6;
  const int wr = wave >> 1, wc = wave & 1;
  const int m0 = blockIdx.y * 128;   // batch rows
  const int n0 = blockIdx.x * 64;    // H cols

  auto stage = [&](int buf, int t) {
    const unsigned short* Ab; const unsigned short* Wb; int KA, k0;
    if (t < 8) { Ab = inp_b; Wb = wih; KA = 512;  k0 = t * 64; }
    else       { Ab = h_b;   Wb = whh; KA = 1024; k0 = (t - 8) * 64; }
    // A tile: 128x64 = 16KB = 1024 x 16B chunks, 4/thread
#pragma unroll
    for (int it = 0; it < 4; ++it) {
      int li   = it * 256 + tid;          // 0..1023
      int row  = li >> 3;                 // 0..127
      int slot = li & 7;
      int cb   = slot ^ (row & 7);        // inverse swizzle on global source
      GLOAD(Ab + (size_t)(m0 + row) * KA + k0 + cb * 8, &lsA[buf][li * 8]);
    }
    // W tiles: 3 x 64 x 64 = 24KB = 1536 x 16B chunks, 6/thread
#pragma unroll
    for (int it = 0; it < 6; ++it) {
      int li   = it * 256 + tid;          // 0..1535
      int rowg = li >> 3;                 // 0..191
      int g    = rowg >> 6;
      int prow = rowg & 63;
      int slot = li & 7;
      int cb   = slot ^ (prow & 7);
      GLOAD(Wb + (size_t)(g * 1024 + n0 + prow) * KA + k0 + cb * 8,
            &lsW[buf][li * 8]);
    }
  };

  f32x4 accR[4][2], accZ[4][2], accNi[4][2], accNh[4][2];
#pragma unroll
  for (int m = 0; m < 4; ++m)
#pragma unroll
    for (int n = 0; n < 2; ++n) {
      accR[m][n]  = f32x4{0.f, 0.f, 0.f, 0.f};
      accZ[m][n]  = f32x4{0.f, 0.f, 0.f, 0.f};
      accNi[m][n] = f32x4{0.f, 0.f, 0.f, 0.f};
      accNh[m][n] = f32x4{0.f, 0.f, 0.f, 0.f};
    }

  const int t4 = lane >> 4;               // 0..3 (k sub-block)
  const int rA = wr * 64 + (lane & 15);
  const int rW = wc * 32 + (lane & 15);
  const int sx = lane & 7;                // read-side swizzle XOR (= row&7)

  auto compute = [&](int buf, f32x4 (*accN)[2]) {
#pragma unroll
    for (int ks = 0; ks < 2; ++ks) {
      const int scb = (ks * 4 + t4) ^ sx; // swizzled 16B slot
      bf16x8 af[4], bfr[3][2];
#pragma unroll
      for (int m = 0; m < 4; ++m)
        af[m] = *(const bf16x8*)&lsA[buf][(rA + m * 16) * 64 + scb * 8];
#pragma unroll
      for (int g = 0; g < 3; ++g)
#pragma unroll
        for (int n = 0; n < 2; ++n)
          bfr[g][n] = *(const bf16x8*)&lsW[buf][g * 4096 + (rW + n * 16) * 64 + scb * 8];
      __builtin_amdgcn_s_setprio(1);
#pragma unroll
      for (int m = 0; m < 4; ++m)
#pragma unroll
        for (int n = 0; n < 2; ++n) {
          accR[m][n] = __builtin_amdgcn_mfma_f32_16x16x32_bf16(af[m], bfr[0][n], accR[m][n], 0, 0, 0);
          accZ[m][n] = __builtin_amdgcn_mfma_f32_16x16x32_bf16(af[m], bfr[1][n], accZ[m][n], 0, 0, 0);
          accN[m][n] = __builtin_amdgcn_mfma_f32_16x16x32_bf16(af[m], bfr[2][n], accN[m][n], 0, 0, 0);
        }
      __builtin_amdgcn_s_setprio(0);
    }
  };

  stage(0, 0);
  int buf = 0;
  for (int t = 0; t < 24; ++t) {
    if (t < 23) {
      stage(buf ^ 1, t + 1);
      asm volatile("s_waitcnt vmcnt(10)" ::: "memory");  // tile t landed; t+1 in flight
    } else {
      asm volatile("s_waitcnt vmcnt(0)" ::: "memory");
    }
    __builtin_amdgcn_s_barrier();
    if (t < 8) compute(buf, accNi);
    else       compute(buf, accNh);
    __builtin_amdgcn_s_barrier();
    buf ^= 1;
  }

  // ---- epilogue: gate math + blend ----
  // C/D layout: col = lane&15, row = (lane>>4)*4 + r
  const int colb = n0 + wc * 32 + (lane & 15);
  const int rowb = m0 + wr * 64 + (t4 << 2);
#pragma unroll
  for (int n = 0; n < 2; ++n) {
    int c = colb + n * 16;
    float br  = b_ih[c]        + b_hh[c];
    float bz  = b_ih[1024 + c] + b_hh[1024 + c];
    float bni = b_ih[2048 + c];
    float bnh = b_hh[2048 + c];
#pragma unroll
    for (int m = 0; m < 4; ++m) {
      int row = rowb + m * 16;
#pragma unroll
      for (int r = 0; r < 4; ++r) {
        float rg = sigmoid_f(accR[m][n][r] + br);
        float zg = sigmoid_f(accZ[m][n][r] + bz);
        float ng = tanh_f((accNi[m][n][r] + bni) + rg * (accNh[m][n][r] + bnh));
        float ho = hidden[(size_t)(row + r) * 1024 + c];
        float hv = (1.f - zg) * ng + zg * ho;
        hnew_f32[(size_t)(row + r) * 1024 + c] = hv;
        hnew_b [(size_t)(row + r) * 1024 + c] = f2bf(hv);
      }
    }
  }
}

// ---------- out GEMM: C = tanh(A[M,K] * Bm[N,K]^T + bias), f32 out ----------
__global__ __launch_bounds__(256) void gemm_out(
    const unsigned short* __restrict__ A,
    const unsigned short* __restrict__ Bm,
    float* __restrict__ Cout,
    const float* __restrict__ bias,
    int M, int N, int K)
{
  __shared__ unsigned short lsA[2][128 * 32];
  __shared__ unsigned short lsB[2][128 * 32];

  const int tid  = threadIdx.x;
  const int lane = tid & 63;
  const int wave = tid >> 6;
  const int wr = wave >> 1, wc = wave & 1;
  const int m0 = blockIdx.y * 128;
  const int n0 = blockIdx.x * 128;

  auto stage = [&](int buf, int kt) {
    const int k0 = kt * 32;
#pragma unroll
    for (int it = 0; it < 2; ++it) {
      int li  = it * 256 + tid;
      int row = li >> 2;
      int col = (li & 3) << 3;
      GLOAD(A  + (size_t)(m0 + row) * K + k0 + col, &lsA[buf][li * 8]);
      GLOAD(Bm + (size_t)(n0 + row) * K + k0 + col, &lsB[buf][li * 8]);
    }
  };

  f32x4 acc[4][4];
#pragma unroll
  for (int i = 0; i < 4; ++i)
#pragma unroll
    for (int j = 0; j < 4; ++j) acc[i][j] = f32x4{0.f, 0.f, 0.f, 0.f};

  const int nk = K >> 5;
  stage(0, 0);
  int buf = 0;
  for (int kt = 0; kt < nk; ++kt) {
    if (kt + 1 < nk) {
      stage(buf ^ 1, kt + 1);
      asm volatile("s_waitcnt vmcnt(4)" ::: "memory");
    } else {
      asm volatile("s_waitcnt vmcnt(0)" ::: "memory");
    }
    __builtin_amdgcn_s_barrier();
    const int kofs = (lane >> 4) << 3;
    const int rA = wr * 64 + (lane & 15);
    const int rB = wc * 64 + (lane & 15);
    bf16x8 af[4], bfr[4];
#pragma unroll
    for (int m = 0; m < 4; ++m)
      af[m] = *(const bf16x8*)&lsA[buf][(rA + m * 16) * 32 + kofs];
#pragma unroll
    for (int n = 0; n < 4; ++n)
      bfr[n] = *(const bf16x8*)&lsB[buf][(rB + n * 16) * 32 + kofs];
#pragma unroll
    for (int m = 0; m < 4; ++m)
#pragma unroll
      for (int n = 0; n < 4; ++n)
        acc[m][n] = __builtin_amdgcn_mfma_f32_16x16x32_bf16(af[m], bfr[n], acc[m][n], 0, 0, 0);
    __builtin_amdgcn_s_barrier();
    buf ^= 1;
  }

  const int colb = n0 + wc * 64 + (lane & 15);
  const int rowb = m0 + wr * 64 + ((lane >> 4) << 2);
#pragma unroll
  for (int n = 0; n < 4; ++n) {
    int col = colb + n * 16;
    float bv = bias[col];
#pragma unroll
    for (int m = 0; m < 4; ++m) {
      int row = rowb + m * 16;
#pragma unroll
      for (int r = 0; r < 4; ++r) {
        Cout[(size_t)(row + r) * N + col] = tanh_f(acc[m][n][r] + bv);
      }
    }
  }
}

// ---------- launch ----------
extern "C" void kernel_launch(void* const* d_in, const int* in_sizes, int n_in,
                              void* d_out, int out_size, void* d_ws, size_t ws_size,
                              hipStream_t stream) {
  const int B = 16384, H = 1024, O = 512;
  const float* inp    = (const float*)d_in[0];
  const float* hidden = (const float*)d_in[1];
  const float* w_ih   = (const float*)d_in[2];
  const float* w_hh   = (const float*)d_in[3];
  const float* b_ih   = (const float*)d_in[4];
  const float* b_hh   = (const float*)d_in[5];
  const float* w_out  = (const float*)d_in[6];
  const float* b_out  = (const float*)d_in[7];

  float* out      = (float*)d_out;                     // [B, O] f32
  float* hnew_out = out + (size_t)B * O;               // [1, B, H] f32

  char* ws = (char*)d_ws;
  size_t need = 0;
  auto carve = [&](size_t elems) {
    unsigned short* p = (unsigned short*)(ws + need);
    need += elems * 2;
    return p;
  };
  unsigned short* inp_b  = carve((size_t)B * O);       // 16 MB
  unsigned short* h_b    = carve((size_t)B * H);       // 32 MB
  unsigned short* wih_b  = carve((size_t)3 * H * O);   // 3 MB
  unsigned short* whh_b  = carve((size_t)3 * H * H);   // 6 MB
  unsigned short* wout_b = carve((size_t)O * H);       // 1 MB
  unsigned short* hnew_b = carve((size_t)B * H);       // 32 MB
  if (ws_size < need) return;

  auto cast = [&](const float* src, unsigned short* dst, long n) {
    cast_f32_bf16<<<dim3((unsigned)((n / 8 + 255) / 256)), dim3(256), 0, stream>>>(src, dst, n);
  };
  cast(inp,    inp_b,  (long)B * O);
  cast(hidden, h_b,    (long)B * H);
  cast(w_ih,   wih_b,  (long)3 * H * O);
  cast(w_hh,   whh_b,  (long)3 * H * H);
  cast(w_out,  wout_b, (long)O * H);

  // fused GRU cell -> h_new (f32 into d_out tail, bf16 into ws)
  fused_gru<<<dim3(H / 64, B / 128), dim3(256), 0, stream>>>(
      inp_b, h_b, wih_b, whh_b, b_ih, b_hh, hidden, hnew_out, hnew_b);

  // out = tanh(h_new @ w_out^T + b_out)
  gemm_out<<<dim3(O / 128, B / 128), dim3(256), 0, stream>>>(
      hnew_b, wout_b, out, b_out, B, O, H);
}

// Round 6
// 322.182 us; speedup vs baseline: 3.1268x; 3.1268x over previous
//
#include <hip/hip_runtime.h>

// ---------- types ----------
typedef __bf16 bf16x8 __attribute__((ext_vector_type(8)));
typedef float  f32x4  __attribute__((ext_vector_type(4)));
typedef unsigned short us8 __attribute__((ext_vector_type(8)));

__device__ __forceinline__ unsigned short f2bf(float f) {
  unsigned int u = __builtin_bit_cast(unsigned int, f);
  u += 0x7FFFu + ((u >> 16) & 1u);   // round-to-nearest-even
  return (unsigned short)(u >> 16);
}
__device__ __forceinline__ float bf2f(unsigned short h) {
  unsigned int u = ((unsigned int)h) << 16;
  return __builtin_bit_cast(float, u);
}
__device__ __forceinline__ float sigmoid_f(float x) {
  return 1.f / (1.f + __expf(-x));
}
// NaN-safe fast tanh: 1 - 2/(e^{2x}+1)
__device__ __forceinline__ float tanh_f(float x) {
  float e = __expf(2.f * x);
  return 1.f - 2.f / (e + 1.f);
}

// ---------- f32 -> bf16 cast, 8 elems/thread ----------
__global__ void cast_f32_bf16(const float* __restrict__ in,
                              unsigned short* __restrict__ out, long n) {
  long i = ((long)blockIdx.x * blockDim.x + threadIdx.x) * 8;
  if (i >= n) return;
  f32x4 a = *(const f32x4*)(in + i);
  f32x4 b = *(const f32x4*)(in + i + 4);
  us8 o;
  o[0] = f2bf(a[0]); o[1] = f2bf(a[1]); o[2] = f2bf(a[2]); o[3] = f2bf(a[3]);
  o[4] = f2bf(b[0]); o[5] = f2bf(b[1]); o[6] = f2bf(b[2]); o[7] = f2bf(b[3]);
  *(us8*)(out + i) = o;
}

#define GLOAD(gp, lp) __builtin_amdgcn_global_load_lds( \
    (const __attribute__((address_space(1))) unsigned int*)(gp), \
    (__attribute__((address_space(3))) unsigned int*)(lp), 16, 0, 0)

// ---------- Fused GRU cell (round-4 structure + slot-major LDS subtiles) ----------
// Block tile: 128 batch-rows x 64 H-cols (x3 gates). 4 waves (2M x 2C),
// wave tile 64x32 per gate-accumulator. Acc sets: r, z, i_n, h_n.
// LDS layout: each 1KB region = 16 rows x 4 k-slots of 16B, stored SLOT-MAJOR
// (p = slot*16 + row) so the 16 lanes of a fragment-read hit consecutive 16B
// chunks (conflict-free). gload_lds dest stays linear; the permutation is on
// the per-lane global source (rule #21). Per tile: 5 gload_lds/thread;
// s_waitcnt vmcnt(5) keeps the next tile's loads in flight (T4).
__global__ __launch_bounds__(256, 2) void fused_gru(
    const unsigned short* __restrict__ inp_b,
    const unsigned short* __restrict__ h_b,
    const unsigned short* __restrict__ wih,
    const unsigned short* __restrict__ whh,
    const float* __restrict__ b_ih,
    const float* __restrict__ b_hh,
    const float* __restrict__ hidden,      // [B,1024] f32
    float* __restrict__ hnew_f32,
    unsigned short* __restrict__ hnew_b)
{
  __shared__ unsigned short lsA[2][128 * 32];      // 2 x 8KB  (8 regions)
  __shared__ unsigned short lsW[2][3 * 64 * 32];   // 2 x 12KB (3 gates x 4 regions)

  const int tid  = threadIdx.x;
  const int lane = tid & 63;
  const int wave = tid >> 6;
  const int wr = wave >> 1, wc = wave & 1;
  const int m0 = blockIdx.y * 128;   // batch rows
  const int n0 = blockIdx.x * 64;    // H cols

  auto stage = [&](int buf, const unsigned short* Abase, const unsigned short* Wbase,
                   int KA, int kt) {
    const int k0 = kt * 32;
    // A tile: 128x32 = 8KB = 512 x 16B chunks; chunk li -> region li>>6,
    // within-region p = li&63: row = (li>>6)*16 + (p&15), kslot = p>>4
#pragma unroll
    for (int it = 0; it < 2; ++it) {
      int li = it * 256 + tid;              // 0..511
      int p  = li & 63;
      int row = ((li >> 6) << 4) + (p & 15);
      int s   = p >> 4;                     // 0..3
      GLOAD(Abase + (size_t)(m0 + row) * KA + k0 + s * 8, &lsA[buf][li * 8]);
    }
    // W tiles: 3 x 64 x 32 = 12KB = 768 chunks; gate g = li>>8, q = li&255
#pragma unroll
    for (int it = 0; it < 3; ++it) {
      int li = it * 256 + tid;              // 0..767
      int g  = li >> 8;
      int q  = li & 255;
      int p  = q & 63;
      int row = ((q >> 6) << 4) + (p & 15); // row within 64-row panel
      int s   = p >> 4;
      GLOAD(Wbase + (size_t)(g * 1024 + n0 + row) * KA + k0 + s * 8,
            &lsW[buf][li * 8]);
    }
  };

  f32x4 accR[4][2], accZ[4][2], accNi[4][2], accNh[4][2];
#pragma unroll
  for (int m = 0; m < 4; ++m)
#pragma unroll
    for (int n = 0; n < 2; ++n) {
      accR[m][n]  = f32x4{0.f, 0.f, 0.f, 0.f};
      accZ[m][n]  = f32x4{0.f, 0.f, 0.f, 0.f};
      accNi[m][n] = f32x4{0.f, 0.f, 0.f, 0.f};
      accNh[m][n] = f32x4{0.f, 0.f, 0.f, 0.f};
    }

  const int t4  = lane >> 4;                 // k-slot 0..3
  const int l15 = lane & 15;
  const int rofs = t4 * 128 + l15 * 8;       // within-region read offset (elems)

  // A fragment (row rA+m*16, k t4*8..): region = wr*4+m  -> elem (wr*4+m)*512+rofs
  // W fragment (row wc*32+n*16+l15): region = wc*2+n within gate panel (512 elems)
  auto compute = [&](int buf, f32x4 (*accN)[2]) {
    bf16x8 af[4], bfr[3][2];
#pragma unroll
    for (int m = 0; m < 4; ++m)
      af[m] = *(const bf16x8*)&lsA[buf][(wr * 4 + m) * 512 + rofs];
#pragma unroll
    for (int g = 0; g < 3; ++g)
#pragma unroll
      for (int n = 0; n < 2; ++n)
        bfr[g][n] = *(const bf16x8*)&lsW[buf][g * 2048 + (wc * 2 + n) * 512 + rofs];
#pragma unroll
    for (int m = 0; m < 4; ++m)
#pragma unroll
      for (int n = 0; n < 2; ++n) {
        accR[m][n] = __builtin_amdgcn_mfma_f32_16x16x32_bf16(af[m], bfr[0][n], accR[m][n], 0, 0, 0);
        accZ[m][n] = __builtin_amdgcn_mfma_f32_16x16x32_bf16(af[m], bfr[1][n], accZ[m][n], 0, 0, 0);
        accN[m][n] = __builtin_amdgcn_mfma_f32_16x16x32_bf16(af[m], bfr[2][n], accN[m][n], 0, 0, 0);
      }
  };

  const int nk0 = 512 >> 5;    // 16
  const int nk1 = 1024 >> 5;   // 32

  int buf = 0;
  stage(0, inp_b, wih, 512, 0);
  // phase 0: A=inp, W=wih
  for (int kt = 0; kt < nk0; ++kt) {
    if (kt + 1 < nk0) stage(buf ^ 1, inp_b, wih, 512, kt + 1);
    else              stage(buf ^ 1, h_b,   whh, 1024, 0);
    asm volatile("s_waitcnt vmcnt(5)" ::: "memory");   // tile kt landed; next 5 in flight
    __builtin_amdgcn_s_barrier();
    compute(buf, accNi);
    __builtin_amdgcn_s_barrier();
    buf ^= 1;
  }
  // phase 1: A=h, W=whh
  for (int kt = 0; kt < nk1; ++kt) {
    if (kt + 1 < nk1) {
      stage(buf ^ 1, h_b, whh, 1024, kt + 1);
      asm volatile("s_waitcnt vmcnt(5)" ::: "memory");
    } else {
      asm volatile("s_waitcnt vmcnt(0)" ::: "memory");
    }
    __builtin_amdgcn_s_barrier();
    compute(buf, accNh);
    __builtin_amdgcn_s_barrier();
    buf ^= 1;
  }

  // ---- epilogue: gate math + blend ----
  // C/D layout: col = lane&15, row = (lane>>4)*4 + r
  const int colb = n0 + wc * 32 + l15;
  const int rowb = m0 + wr * 64 + (t4 << 2);
#pragma unroll
  for (int n = 0; n < 2; ++n) {
    int c = colb + n * 16;
    float br  = b_ih[c]        + b_hh[c];
    float bz  = b_ih[1024 + c] + b_hh[1024 + c];
    float bni = b_ih[2048 + c];
    float bnh = b_hh[2048 + c];
#pragma unroll
    for (int m = 0; m < 4; ++m) {
      int row = rowb + m * 16;
#pragma unroll
      for (int r = 0; r < 4; ++r) {
        float rg = sigmoid_f(accR[m][n][r] + br);
        float zg = sigmoid_f(accZ[m][n][r] + bz);
        float ng = tanh_f((accNi[m][n][r] + bni) + rg * (accNh[m][n][r] + bnh));
        float ho = hidden[(size_t)(row + r) * 1024 + c];
        float hv = (1.f - zg) * ng + zg * ho;
        hnew_f32[(size_t)(row + r) * 1024 + c] = hv;
        hnew_b [(size_t)(row + r) * 1024 + c] = f2bf(hv);
      }
    }
  }
}

// ---------- out GEMM: C = tanh(A[M,K] * Bm[N,K]^T + bias), f32 out ----------
__global__ __launch_bounds__(256) void gemm_out(
    const unsigned short* __restrict__ A,
    const unsigned short* __restrict__ Bm,
    float* __restrict__ Cout,
    const float* __restrict__ bias,
    int M, int N, int K)
{
  __shared__ unsigned short lsA[2][128 * 32];
  __shared__ unsigned short lsB[2][128 * 32];

  const int tid  = threadIdx.x;
  const int lane = tid & 63;
  const int wave = tid >> 6;
  const int wr = wave >> 1, wc = wave & 1;
  const int m0 = blockIdx.y * 128;
  const int n0 = blockIdx.x * 128;

  auto stage = [&](int buf, int kt) {
    const int k0 = kt * 32;
#pragma unroll
    for (int it = 0; it < 2; ++it) {
      int li  = it * 256 + tid;
      int row = li >> 2;
      int col = (li & 3) << 3;
      GLOAD(A  + (size_t)(m0 + row) * K + k0 + col, &lsA[buf][li * 8]);
      GLOAD(Bm + (size_t)(n0 + row) * K + k0 + col, &lsB[buf][li * 8]);
    }
  };

  f32x4 acc[4][4];
#pragma unroll
  for (int i = 0; i < 4; ++i)
#pragma unroll
    for (int j = 0; j < 4; ++j) acc[i][j] = f32x4{0.f, 0.f, 0.f, 0.f};

  const int nk = K >> 5;
  stage(0, 0);
  int buf = 0;
  for (int kt = 0; kt < nk; ++kt) {
    if (kt + 1 < nk) {
      stage(buf ^ 1, kt + 1);
      asm volatile("s_waitcnt vmcnt(4)" ::: "memory");
    } else {
      asm volatile("s_waitcnt vmcnt(0)" ::: "memory");
    }
    __builtin_amdgcn_s_barrier();
    const int kofs = (lane >> 4) << 3;
    const int rA = wr * 64 + (lane & 15);
    const int rB = wc * 64 + (lane & 15);
    bf16x8 af[4], bfr[4];
#pragma unroll
    for (int m = 0; m < 4; ++m)
      af[m] = *(const bf16x8*)&lsA[buf][(rA + m * 16) * 32 + kofs];
#pragma unroll
    for (int n = 0; n < 4; ++n)
      bfr[n] = *(const bf16x8*)&lsB[buf][(rB + n * 16) * 32 + kofs];
#pragma unroll
    for (int m = 0; m < 4; ++m)
#pragma unroll
      for (int n = 0; n < 4; ++n)
        acc[m][n] = __builtin_amdgcn_mfma_f32_16x16x32_bf16(af[m], bfr[n], acc[m][n], 0, 0, 0);
    __builtin_amdgcn_s_barrier();
    buf ^= 1;
  }

  const int colb = n0 + wc * 64 + (lane & 15);
  const int rowb = m0 + wr * 64 + ((lane >> 4) << 2);
#pragma unroll
  for (int n = 0; n < 4; ++n) {
    int col = colb + n * 16;
    float bv = bias[col];
#pragma unroll
    for (int m = 0; m < 4; ++m) {
      int row = rowb + m * 16;
#pragma unroll
      for (int r = 0; r < 4; ++r) {
        Cout[(size_t)(row + r) * N + col] = tanh_f(acc[m][n][r] + bv);
      }
    }
  }
}

// ---------- launch ----------
extern "C" void kernel_launch(void* const* d_in, const int* in_sizes, int n_in,
                              void* d_out, int out_size, void* d_ws, size_t ws_size,
                              hipStream_t stream) {
  const int B = 16384, H = 1024, O = 512;
  const float* inp    = (const float*)d_in[0];
  const float* hidden = (const float*)d_in[1];
  const float* w_ih   = (const float*)d_in[2];
  const float* w_hh   = (const float*)d_in[3];
  const float* b_ih   = (const float*)d_in[4];
  const float* b_hh   = (const float*)d_in[5];
  const float* w_out  = (const float*)d_in[6];
  const float* b_out  = (const float*)d_in[7];

  float* out      = (float*)d_out;                     // [B, O] f32
  float* hnew_out = out + (size_t)B * O;               // [1, B, H] f32

  char* ws = (char*)d_ws;
  size_t need = 0;
  auto carve = [&](size_t elems) {
    unsigned short* p = (unsigned short*)(ws + need);
    need += elems * 2;
    return p;
  };
  unsigned short* inp_b  = carve((size_t)B * O);       // 16 MB
  unsigned short* h_b    = carve((size_t)B * H);       // 32 MB
  unsigned short* wih_b  = carve((size_t)3 * H * O);   // 3 MB
  unsigned short* whh_b  = carve((size_t)3 * H * H);   // 6 MB
  unsigned short* wout_b = carve((size_t)O * H);       // 1 MB
  unsigned short* hnew_b = carve((size_t)B * H);       // 32 MB
  if (ws_size < need) return;

  auto cast = [&](const float* src, unsigned short* dst, long n) {
    cast_f32_bf16<<<dim3((unsigned)((n / 8 + 255) / 256)), dim3(256), 0, stream>>>(src, dst, n);
  };
  cast(inp,    inp_b,  (long)B * O);
  cast(hidden, h_b,    (long)B * H);
  cast(w_ih,   wih_b,  (long)3 * H * O);
  cast(w_hh,   whh_b,  (long)3 * H * H);
  cast(w_out,  wout_b, (long)O * H);

  // fused GRU cell -> h_new (f32 into d_out tail, bf16 into ws)
  fused_gru<<<dim3(H / 64, B / 128), dim3(256), 0, stream>>>(
      inp_b, h_b, wih_b, whh_b, b_ih, b_hh, hidden, hnew_out, hnew_b);

  // out = tanh(h_new @ w_out^T + b_out)
  gemm_out<<<dim3(O / 128, B / 128), dim3(256), 0, stream>>>(
      hnew_b, wout_b, out, b_out, B, O, H);
}

// Round 7
// 255.691 us; speedup vs baseline: 3.9399x; 1.2600x over previous
//
#include <hip/hip_runtime.h>

// ---------- types ----------
typedef __bf16 bf16x8 __attribute__((ext_vector_type(8)));
typedef float  f32x4  __attribute__((ext_vector_type(4)));
typedef unsigned short us8 __attribute__((ext_vector_type(8)));

__device__ __forceinline__ unsigned short f2bf(float f) {
  unsigned int u = __builtin_bit_cast(unsigned int, f);
  u += 0x7FFFu + ((u >> 16) & 1u);   // round-to-nearest-even
  return (unsigned short)(u >> 16);
}
__device__ __forceinline__ float sigmoid_f(float x) {
  return 1.f / (1.f + __expf(-x));
}
// NaN-safe fast tanh: 1 - 2/(e^{2x}+1)
__device__ __forceinline__ float tanh_f(float x) {
  float e = __expf(2.f * x);
  return 1.f - 2.f / (e + 1.f);
}

// ---------- plain f32 -> bf16 cast, 8 elems/thread (for w_out only) ----------
__global__ void cast_f32_bf16(const float* __restrict__ in,
                              unsigned short* __restrict__ out, long n) {
  long i = ((long)blockIdx.x * blockDim.x + threadIdx.x) * 8;
  if (i >= n) return;
  f32x4 a = *(const f32x4*)(in + i);
  f32x4 b = *(const f32x4*)(in + i + 4);
  us8 o;
  o[0] = f2bf(a[0]); o[1] = f2bf(a[1]); o[2] = f2bf(a[2]); o[3] = f2bf(a[3]);
  o[4] = f2bf(b[0]); o[5] = f2bf(b[1]); o[6] = f2bf(b[2]); o[7] = f2bf(b[3]);
  *(us8*)(out + i) = o;
}

// ---------- cast+relayout: one wave converts a 16row x 32col f32 region to
// slot-major bf16 (region image: elem = s4*128 + r16*8 + e). Coalesced global
// reads (lane l: row l>>2, 32B), transpose via +1-padded LDS, contiguous 16B
// writes (lane l -> dst[l*8]). ----------
__device__ __forceinline__ void relayout_region(
    const float* __restrict__ srcRowBase, size_t rowStride,
    unsigned short* __restrict__ dst, float* __restrict__ lp, int lane) {
  {
    int r = lane >> 2, c = (lane & 3) << 3;
    const float* s = srcRowBase + (size_t)r * rowStride + c;
    f32x4 a = *(const f32x4*)(s);
    f32x4 b = *(const f32x4*)(s + 4);
#pragma unroll
    for (int j = 0; j < 4; ++j) { lp[r * 33 + c + j] = a[j]; lp[r * 33 + c + 4 + j] = b[j]; }
  }
  int s4 = lane >> 4, r16 = lane & 15;
  us8 o;
#pragma unroll
  for (int j = 0; j < 8; ++j) o[j] = f2bf(lp[r16 * 33 + s4 * 8 + j]);
  *(us8*)(dst + lane * 8) = o;
}

// A relayout: wave gw = (p * nkt + kt); tile = rows [p*128, p*128+128) x k [kt*32, +32)
// dst tile = 4096 elems = 8 regions of 512 (region g holds rows g*16..+15)
__global__ __launch_bounds__(256) void relayout_A(
    const float* __restrict__ src, unsigned short* __restrict__ dst, int K) {
  __shared__ float lp[4][16 * 33];
  const int wIn = threadIdx.x >> 6, lane = threadIdx.x & 63;
  const int gw  = blockIdx.x * 4 + wIn;
  const int nkt = K >> 5;
  const int p = gw / nkt, kt = gw - p * nkt;
  const float* base = src + (size_t)p * 128 * K + kt * 32;
  unsigned short* d = dst + (size_t)gw * 4096;
#pragma unroll
  for (int g = 0; g < 8; ++g)
    relayout_region(base + (size_t)g * 16 * K, K, d + g * 512, lp[wIn], lane);
}

// W relayout: wave gw = ((q*3 + g) * nkt + kt); panel = gate g, rows [q*64,+64)
// dst tile = 2048 elems = 4 regions of 512
__global__ __launch_bounds__(256) void relayout_W(
    const float* __restrict__ src, unsigned short* __restrict__ dst, int K) {
  __shared__ float lp[4][16 * 33];
  const int wIn = threadIdx.x >> 6, lane = threadIdx.x & 63;
  const int gw  = blockIdx.x * 4 + wIn;
  const int nkt = K >> 5;
  const int qg = gw / nkt, kt = gw - qg * nkt;
  const int q = qg / 3, g = qg - q * 3;
  const float* base = src + ((size_t)g * 1024 + q * 64) * K + kt * 32;
  unsigned short* d = dst + (size_t)gw * 2048;
#pragma unroll
  for (int rg = 0; rg < 4; ++rg)
    relayout_region(base + (size_t)rg * 16 * K, K, d + rg * 512, lp[wIn], lane);
}

#define GLOAD(gp, lp) __builtin_amdgcn_global_load_lds( \
    (const __attribute__((address_space(1))) unsigned int*)(gp), \
    (__attribute__((address_space(3))) unsigned int*)(lp), 16, 0, 0)

// ---------- Fused GRU cell: round-4 schedule + round-6 conflict-free LDS,
// staged from pre-relayouted global (fully linear per-wave gload_lds). ----------
__global__ __launch_bounds__(256, 2) void fused_gru(
    const unsigned short* __restrict__ inp_r,
    const unsigned short* __restrict__ h_r,
    const unsigned short* __restrict__ wih_r,
    const unsigned short* __restrict__ whh_r,
    const float* __restrict__ b_ih,
    const float* __restrict__ b_hh,
    const float* __restrict__ hidden,      // [B,1024] f32
    float* __restrict__ hnew_f32,
    unsigned short* __restrict__ hnew_b)
{
  __shared__ unsigned short lsA[2][128 * 32];      // 2 x 8KB  (8 regions)
  __shared__ unsigned short lsW[2][3 * 64 * 32];   // 2 x 12KB (3 gates x 4 regions)

  const int tid  = threadIdx.x;
  const int lane = tid & 63;
  const int wave = tid >> 6;
  const int wr = wave >> 1, wc = wave & 1;

  // stage: per K-tile, A tile = 4096 elems (2 chunks/thread), W = 3 x 2048
  // (3 chunks/thread). All per-wave global runs are contiguous 1KB.
  auto stage = [&](int buf, const unsigned short* Ar, const unsigned short* Wr,
                   int nkt, int kt) {
    const unsigned short* abase = Ar + ((size_t)(blockIdx.y * nkt + kt)) * 4096;
#pragma unroll
    for (int it = 0; it < 2; ++it) {
      int li = it * 256 + tid;
      GLOAD(abase + li * 8, &lsA[buf][li * 8]);
    }
#pragma unroll
    for (int g = 0; g < 3; ++g) {
      const unsigned short* wbase =
          Wr + ((size_t)((blockIdx.x * 3 + g) * nkt + kt)) * 2048;
      GLOAD(wbase + tid * 8, &lsW[buf][(g * 256 + tid) * 8]);
    }
  };

  f32x4 accR[4][2], accZ[4][2], accNi[4][2], accNh[4][2];
#pragma unroll
  for (int m = 0; m < 4; ++m)
#pragma unroll
    for (int n = 0; n < 2; ++n) {
      accR[m][n]  = f32x4{0.f, 0.f, 0.f, 0.f};
      accZ[m][n]  = f32x4{0.f, 0.f, 0.f, 0.f};
      accNi[m][n] = f32x4{0.f, 0.f, 0.f, 0.f};
      accNh[m][n] = f32x4{0.f, 0.f, 0.f, 0.f};
    }

  const int t4   = lane >> 4;                // k-octet 0..3
  const int l15  = lane & 15;
  const int rofs = t4 * 128 + l15 * 8;       // within-region read offset (elems)

  auto compute = [&](int buf, f32x4 (*accN)[2]) {
    bf16x8 af[4], bfr[3][2];
#pragma unroll
    for (int m = 0; m < 4; ++m)
      af[m] = *(const bf16x8*)&lsA[buf][(wr * 4 + m) * 512 + rofs];
#pragma unroll
    for (int g = 0; g < 3; ++g)
#pragma unroll
      for (int n = 0; n < 2; ++n)
        bfr[g][n] = *(const bf16x8*)&lsW[buf][g * 2048 + (wc * 2 + n) * 512 + rofs];
#pragma unroll
    for (int m = 0; m < 4; ++m)
#pragma unroll
      for (int n = 0; n < 2; ++n) {
        accR[m][n] = __builtin_amdgcn_mfma_f32_16x16x32_bf16(af[m], bfr[0][n], accR[m][n], 0, 0, 0);
        accZ[m][n] = __builtin_amdgcn_mfma_f32_16x16x32_bf16(af[m], bfr[1][n], accZ[m][n], 0, 0, 0);
        accN[m][n] = __builtin_amdgcn_mfma_f32_16x16x32_bf16(af[m], bfr[2][n], accN[m][n], 0, 0, 0);
      }
  };

  const int nk0 = 16;   // K=512
  const int nk1 = 32;   // K=1024

  int buf = 0;
  stage(0, inp_r, wih_r, nk0, 0);
  for (int kt = 0; kt < nk0; ++kt) {
    if (kt + 1 < nk0) stage(buf ^ 1, inp_r, wih_r, nk0, kt + 1);
    else              stage(buf ^ 1, h_r,   whh_r, nk1, 0);
    asm volatile("s_waitcnt vmcnt(5)" ::: "memory");   // tile kt landed; next 5 in flight
    __builtin_amdgcn_s_barrier();
    compute(buf, accNi);
    __builtin_amdgcn_s_barrier();
    buf ^= 1;
  }
  for (int kt = 0; kt < nk1; ++kt) {
    if (kt + 1 < nk1) {
      stage(buf ^ 1, h_r, whh_r, nk1, kt + 1);
      asm volatile("s_waitcnt vmcnt(5)" ::: "memory");
    } else {
      asm volatile("s_waitcnt vmcnt(0)" ::: "memory");
    }
    __builtin_amdgcn_s_barrier();
    compute(buf, accNh);
    __builtin_amdgcn_s_barrier();
    buf ^= 1;
  }

  // ---- epilogue: gate math + blend ----
  // C/D layout: col = lane&15, row = (lane>>4)*4 + r
  const int m0 = blockIdx.y * 128;
  const int n0 = blockIdx.x * 64;
  const int colb = n0 + wc * 32 + l15;
  const int rowb = m0 + wr * 64 + (t4 << 2);
#pragma unroll
  for (int n = 0; n < 2; ++n) {
    int c = colb + n * 16;
    float br  = b_ih[c]        + b_hh[c];
    float bz  = b_ih[1024 + c] + b_hh[1024 + c];
    float bni = b_ih[2048 + c];
    float bnh = b_hh[2048 + c];
#pragma unroll
    for (int m = 0; m < 4; ++m) {
      int row = rowb + m * 16;
#pragma unroll
      for (int r = 0; r < 4; ++r) {
        float rg = sigmoid_f(accR[m][n][r] + br);
        float zg = sigmoid_f(accZ[m][n][r] + bz);
        float ng = tanh_f((accNi[m][n][r] + bni) + rg * (accNh[m][n][r] + bnh));
        float ho = hidden[(size_t)(row + r) * 1024 + c];
        float hv = (1.f - zg) * ng + zg * ho;
        hnew_f32[(size_t)(row + r) * 1024 + c] = hv;
        hnew_b [(size_t)(row + r) * 1024 + c] = f2bf(hv);
      }
    }
  }
}

// ---------- out GEMM: C = tanh(A[M,K] * Bm[N,K]^T + bias), f32 out ----------
__global__ __launch_bounds__(256) void gemm_out(
    const unsigned short* __restrict__ A,
    const unsigned short* __restrict__ Bm,
    float* __restrict__ Cout,
    const float* __restrict__ bias,
    int M, int N, int K)
{
  __shared__ unsigned short lsA[2][128 * 32];
  __shared__ unsigned short lsB[2][128 * 32];

  const int tid  = threadIdx.x;
  const int lane = tid & 63;
  const int wave = tid >> 6;
  const int wr = wave >> 1, wc = wave & 1;
  const int m0 = blockIdx.y * 128;
  const int n0 = blockIdx.x * 128;

  auto stage = [&](int buf, int kt) {
    const int k0 = kt * 32;
#pragma unroll
    for (int it = 0; it < 2; ++it) {
      int li  = it * 256 + tid;
      int row = li >> 2;
      int col = (li & 3) << 3;
      GLOAD(A  + (size_t)(m0 + row) * K + k0 + col, &lsA[buf][li * 8]);
      GLOAD(Bm + (size_t)(n0 + row) * K + k0 + col, &lsB[buf][li * 8]);
    }
  };

  f32x4 acc[4][4];
#pragma unroll
  for (int i = 0; i < 4; ++i)
#pragma unroll
    for (int j = 0; j < 4; ++j) acc[i][j] = f32x4{0.f, 0.f, 0.f, 0.f};

  const int nk = K >> 5;
  stage(0, 0);
  int buf = 0;
  for (int kt = 0; kt < nk; ++kt) {
    if (kt + 1 < nk) {
      stage(buf ^ 1, kt + 1);
      asm volatile("s_waitcnt vmcnt(4)" ::: "memory");
    } else {
      asm volatile("s_waitcnt vmcnt(0)" ::: "memory");
    }
    __builtin_amdgcn_s_barrier();
    const int kofs = (lane >> 4) << 3;
    const int rA = wr * 64 + (lane & 15);
    const int rB = wc * 64 + (lane & 15);
    bf16x8 af[4], bfr[4];
#pragma unroll
    for (int m = 0; m < 4; ++m)
      af[m] = *(const bf16x8*)&lsA[buf][(rA + m * 16) * 32 + kofs];
#pragma unroll
    for (int n = 0; n < 4; ++n)
      bfr[n] = *(const bf16x8*)&lsB[buf][(rB + n * 16) * 32 + kofs];
#pragma unroll
    for (int m = 0; m < 4; ++m)
#pragma unroll
      for (int n = 0; n < 4; ++n)
        acc[m][n] = __builtin_amdgcn_mfma_f32_16x16x32_bf16(af[m], bfr[n], acc[m][n], 0, 0, 0);
    __builtin_amdgcn_s_barrier();
    buf ^= 1;
  }

  const int colb = n0 + wc * 64 + (lane & 15);
  const int rowb = m0 + wr * 64 + ((lane >> 4) << 2);
#pragma unroll
  for (int n = 0; n < 4; ++n) {
    int col = colb + n * 16;
    float bv = bias[col];
#pragma unroll
    for (int m = 0; m < 4; ++m) {
      int row = rowb + m * 16;
#pragma unroll
      for (int r = 0; r < 4; ++r) {
        Cout[(size_t)(row + r) * N + col] = tanh_f(acc[m][n][r] + bv);
      }
    }
  }
}

// ---------- launch ----------
extern "C" void kernel_launch(void* const* d_in, const int* in_sizes, int n_in,
                              void* d_out, int out_size, void* d_ws, size_t ws_size,
                              hipStream_t stream) {
  const int B = 16384, H = 1024, O = 512;
  const float* inp    = (const float*)d_in[0];
  const float* hidden = (const float*)d_in[1];
  const float* w_ih   = (const float*)d_in[2];
  const float* w_hh   = (const float*)d_in[3];
  const float* b_ih   = (const float*)d_in[4];
  const float* b_hh   = (const float*)d_in[5];
  const float* w_out  = (const float*)d_in[6];
  const float* b_out  = (const float*)d_in[7];

  float* out      = (float*)d_out;                     // [B, O] f32
  float* hnew_out = out + (size_t)B * O;               // [1, B, H] f32

  char* ws = (char*)d_ws;
  size_t need = 0;
  auto carve = [&](size_t elems) {
    unsigned short* p = (unsigned short*)(ws + need);
    need += elems * 2;
    return p;
  };
  unsigned short* inp_r  = carve((size_t)B * O);       // 16 MB (relayout)
  unsigned short* h_r    = carve((size_t)B * H);       // 32 MB (relayout)
  unsigned short* wih_r  = carve((size_t)3 * H * O);   // 3 MB (relayout)
  unsigned short* whh_r  = carve((size_t)3 * H * H);   // 6 MB (relayout)
  unsigned short* wout_b = carve((size_t)O * H);       // 1 MB (plain)
  unsigned short* hnew_b = carve((size_t)B * H);       // 32 MB (row-major)
  if (ws_size < need) return;

  // cast+relayout (wave = 128x32 A-tile / 64x32 W-panel-tile)
  relayout_A<<<dim3((B / 128) * (O / 32) / 4), dim3(256), 0, stream>>>(inp, inp_r, O);
  relayout_A<<<dim3((B / 128) * (H / 32) / 4), dim3(256), 0, stream>>>(hidden, h_r, H);
  relayout_W<<<dim3((H / 64) * 3 * (O / 32) / 4), dim3(256), 0, stream>>>(w_ih, wih_r, O);
  relayout_W<<<dim3((H / 64) * 3 * (H / 32) / 4), dim3(256), 0, stream>>>(w_hh, whh_r, H);
  cast_f32_bf16<<<dim3((unsigned)(((size_t)O * H / 8 + 255) / 256)), dim3(256), 0, stream>>>(
      w_out, wout_b, (long)O * H);

  // fused GRU cell -> h_new (f32 into d_out tail, bf16 into ws)
  fused_gru<<<dim3(H / 64, B / 128), dim3(256), 0, stream>>>(
      inp_r, h_r, wih_r, whh_r, b_ih, b_hh, hidden, hnew_out, hnew_b);

  // out = tanh(h_new @ w_out^T + b_out)
  gemm_out<<<dim3(O / 128, B / 128), dim3(256), 0, stream>>>(
      hnew_b, wout_b, out, b_out, B, O, H);
}